// Round 4
// baseline (507.180 us; speedup 1.0000x reference)
//
#include <hip/hip_runtime.h>
#include <hip/hip_bf16.h>

typedef __hip_bfloat16 bf16;
typedef short bf16x8 __attribute__((ext_vector_type(8)));
typedef short bf16x4 __attribute__((ext_vector_type(4)));
typedef float f32x4 __attribute__((ext_vector_type(4)));

#define NB 8      // batch
#define SM 512    // block size M
#define SL 1024   // attn span L
#define SH 512    // hidden
#define NH 8      // heads
#define HD 64     // head dim
#define SN 1536   // M + L (key length)

static __device__ __forceinline__ short bf_bits(float x) {
  union { bf16 b; short s; } u; u.b = __float2bfloat16(x); return u.s;
}
// 8 contiguous bf16 -> fragment
static __device__ __forceinline__ bf16x8 ld8any(const bf16* p) {
  return *reinterpret_cast<const bf16x8*>(p);
}
// 8 contiguous f32 -> cvt -> fragment (two dwordx4 loads + pack)
static __device__ __forceinline__ bf16x8 ld8any(const float* p) {
  float4 a = *reinterpret_cast<const float4*>(p);
  float4 b = *reinterpret_cast<const float4*>(p + 4);
  bf16x8 r;
  r[0] = bf_bits(a.x); r[1] = bf_bits(a.y); r[2] = bf_bits(a.z); r[3] = bf_bits(a.w);
  r[4] = bf_bits(b.x); r[5] = bf_bits(b.y); r[6] = bf_bits(b.z); r[7] = bf_bits(b.w);
  return r;
}
static __device__ __forceinline__ void st1(bf16* p, float v) { *p = __float2bfloat16(v); }
static __device__ __forceinline__ void st1(float* p, float v) { *p = v; }

static __device__ __forceinline__ f32x4 mfma16(bf16x8 a, bf16x8 b, f32x4 c) {
  return __builtin_amdgcn_mfma_f32_16x16x32_bf16(a, b, c, 0, 0, 0);
}

// ---------------------------------------------------------------------------
// Y[R x 512] = X[R x 512] @ W^T   (W row-major [512 x 512])
// wave: 16x64 tile; block (4 waves) = 64x64. grid = (R/64, 8)
// ---------------------------------------------------------------------------
template <typename TX, typename TW, typename TY>
__global__ __launch_bounds__(256) void gemm_bt(const TX* __restrict__ X,
                                               const TW* __restrict__ W,
                                               TY* __restrict__ Y) {
  const int lane  = threadIdx.x & 63;
  const int wave  = threadIdx.x >> 6;
  const int col16 = lane & 15;
  const int kq    = (lane >> 4) << 3;
  const int m0 = blockIdx.x * 64 + wave * 16;
  const int n0 = blockIdx.y * 64;
  const TX* xr = X + (size_t)(m0 + col16) * SH + kq;
  const TW* wr = W + (size_t)(n0 + col16) * SH + kq;
  f32x4 a0 = {0.f,0.f,0.f,0.f}, a1 = a0, a2 = a0, a3 = a0;
#pragma unroll
  for (int k0 = 0; k0 < SH; k0 += 32) {
    bf16x8 av = ld8any(xr + k0);
    a0 = mfma16(av, ld8any(wr + k0),           a0);
    a1 = mfma16(av, ld8any(wr + 16*SH + k0),   a1);
    a2 = mfma16(av, ld8any(wr + 32*SH + k0),   a2);
    a3 = mfma16(av, ld8any(wr + 48*SH + k0),   a3);
  }
  const int r0 = m0 + ((lane >> 4) << 2);
#pragma unroll
  for (int r = 0; r < 4; ++r) {
    TY* yr = Y + (size_t)(r0 + r) * SH + n0 + col16;
    st1(yr,      a0[r]);
    st1(yr + 16, a1[r]);
    st1(yr + 32, a2[r]);
    st1(yr + 48, a3[r]);
  }
}

// ---------------------------------------------------------------------------
// V projection fused with per-head transpose:
// vT[(b*8+h)*64 + d][s] = (value @ Wv^T)[b*1536 + s][h*64 + d]
// grid = (rows/64, 8 heads); works for full (rows=12288) or one batch (1536).
// ---------------------------------------------------------------------------
__global__ __launch_bounds__(256) void gemm_v_t(const float* __restrict__ X,
                                                const float* __restrict__ W,
                                                bf16* __restrict__ VT) {
  const int lane  = threadIdx.x & 63;
  const int wave  = threadIdx.x >> 6;
  const int col16 = lane & 15;
  const int kq    = (lane >> 4) << 3;
  const int m0 = blockIdx.x * 64 + wave * 16;
  const int h  = blockIdx.y;
  const float* xr = X + (size_t)(m0 + col16) * SH + kq;
  const float* wr = W + (size_t)(h * HD + col16) * SH + kq;
  f32x4 a0 = {0.f,0.f,0.f,0.f}, a1 = a0, a2 = a0, a3 = a0;
#pragma unroll
  for (int k0 = 0; k0 < SH; k0 += 32) {
    bf16x8 av = ld8any(xr + k0);
    a0 = mfma16(av, ld8any(wr + k0),           a0);
    a1 = mfma16(av, ld8any(wr + 16*SH + k0),   a1);
    a2 = mfma16(av, ld8any(wr + 32*SH + k0),   a2);
    a3 = mfma16(av, ld8any(wr + 48*SH + k0),   a3);
  }
  const int b  = m0 / SN;
  const int s0 = (m0 % SN) + ((lane >> 4) << 2);  // 4 consecutive s per lane
  bf16* vb = VT + (size_t)((b * NH + h) * HD) * SN;
  f32x4 acc[4] = {a0, a1, a2, a3};
#pragma unroll
  for (int t = 0; t < 4; ++t) {
    bf16x4 o;
    o[0] = bf_bits(acc[t][0]); o[1] = bf_bits(acc[t][1]);
    o[2] = bf_bits(acc[t][2]); o[3] = bf_bits(acc[t][3]);
    *reinterpret_cast<bf16x4*>(vb + (size_t)(col16 + t*16) * SN + s0) = o;
  }
}

// ---------------------------------------------------------------------------
// peT[l][d] = bf16(pe[d][l])    (64 x 1024 f32 -> 1024 x 64 bf16)
// ---------------------------------------------------------------------------
__global__ void transpose_pe(const float* __restrict__ pe, bf16* __restrict__ peT) {
  int idx = blockIdx.x * 256 + threadIdx.x;     // 65536 total
  int l = idx >> 6, d = idx & 63;
  peT[idx] = __float2bfloat16(pe[d * SL + l]);
}

// ---------------------------------------------------------------------------
// Fused: per-(batch,head) Q projection + sliding-window attention.
// grid = (16 m-tiles, NHB) where NHB = 64 (full batch) or 8 (one batch).
// ---------------------------------------------------------------------------
#define MT 32
#define CSTR 100   // cont_lds f32 row stride (96 + pad)
#define PSTR 68    // pos_lds  f32 row stride (64 + pad)
#define BSTR 104   // P_lds bf16 row stride (96 + pad, 16B-multiple rows)
#define QSTR 72    // q_lds bf16 row stride (64 + pad, 16B-multiple rows)

__global__ __launch_bounds__(256) void attn_kernel(
    const float* __restrict__ query, const float* __restrict__ Wq,
    const bf16* __restrict__ Kp, const bf16* __restrict__ VT,
    const bf16* __restrict__ peT, const float* __restrict__ spanv,
    bf16* __restrict__ ctx) {
  __shared__ __align__(16) float cont_lds[MT][CSTR];
  __shared__ __align__(16) float pos_lds[MT][PSTR];
  __shared__ __align__(16) bf16  P_lds[MT][BSTR];
  __shared__ __align__(16) bf16  q_lds[MT][QSTR];
  __shared__ float alpha_lds[MT];
  __shared__ float S_lds[MT];

  const int hb = blockIdx.y;
  const int b = hb >> 3, h = hb & 7;
  const int m0 = blockIdx.x * MT;
  const int tid  = threadIdx.x;
  const int lane = tid & 63;
  const int wave = tid >> 6;
  const int col16 = lane & 15, quad = lane >> 4, kq = quad << 3;
  const int msub = wave & 1;    // 16-row half
  const int wsel = wave >> 1;   // tile interleave selector
  const int wr = msub*16 + (quad << 2);

  // zero P band tile once (band cell positions are chunk-invariant)
  for (int i = tid; i < MT * BSTR; i += 256)
    (&P_lds[0][0])[i] = __float2bfloat16(0.0f);

  // ---- fused Q projection: q_lds[32][64] = query_tile @ Wq[h*64.., :]^T ----
  {
    f32x4 qa0 = {0.f,0.f,0.f,0.f}, qa1 = qa0;
    const float* xq = query + (size_t)(b*SM + m0 + msub*16 + col16) * SH + kq;
    const float* w0 = Wq + (size_t)(h*HD + wsel*32 + col16) * SH + kq;
    const float* w1 = w0 + (size_t)16 * SH;
#pragma unroll
    for (int k0 = 0; k0 < SH; k0 += 32) {
      bf16x8 xa = ld8any(xq + k0);
      qa0 = mfma16(xa, ld8any(w0 + k0), qa0);
      qa1 = mfma16(xa, ld8any(w1 + k0), qa1);
    }
#pragma unroll
    for (int r = 0; r < 4; ++r) {
      q_lds[wr + r][wsel*32 + col16]      = __float2bfloat16(qa0[r]);
      q_lds[wr + r][wsel*32 + 16 + col16] = __float2bfloat16(qa1[r]);
    }
  }
  __syncthreads();
  const bf16x8 qf0 = ld8any(&q_lds[msub*16 + col16][kq]);
  const bf16x8 qf1 = ld8any(&q_lds[msub*16 + col16][kq + 32]);

  const bf16* kb = Kp + (size_t)(b*SN) * SH + h*HD + kq;
  const bf16* vb = VT + (size_t)(hb*HD) * SN;

  const int srow = tid >> 3, sj = tid & 7;   // softmax: 8 threads per row
  float Mrun = -1.0e30f, Srun = 0.0f;
  const float span = spanv[h];
  const int dt0 = wsel * 16, dt1 = (wsel + 2) * 16;
  f32x4 o0 = {0.f,0.f,0.f,0.f}, o1 = o0;

  for (int ch = 0; ch < 16; ++ch) {
    const int l0 = ch << 6;
    const int nb_ = m0 + l0;   // absolute key base; max 1440, +95 < 1536

    // ---- phase 1: MFMA cont (3 n-tiles) + pos (2 l-tiles) -> LDS ----
    f32x4 ca0 = {0.f,0.f,0.f,0.f}, ca1 = ca0, ca2 = ca0, pa0 = ca0, pa1 = ca0;
    {
      const bf16* kr0 = kb + (size_t)(nb_ + wsel*16 + col16) * SH;
      ca0 = mfma16(qf0, ld8any(kr0),           ca0);
      ca0 = mfma16(qf1, ld8any(kr0 + 32),      ca0);
      const bf16* kr1 = kr0 + (size_t)32 * SH;
      ca1 = mfma16(qf0, ld8any(kr1),           ca1);
      ca1 = mfma16(qf1, ld8any(kr1 + 32),      ca1);
      const bf16* kr2 = kr0 + (size_t)64 * SH;
      ca2 = mfma16(qf0, ld8any(kr2),           ca2);
      ca2 = mfma16(qf1, ld8any(kr2 + 32),      ca2);
      const bf16* pr0 = peT + (size_t)(l0 + wsel*16 + col16) * HD + kq;
      pa0 = mfma16(qf0, ld8any(pr0),           pa0);
      pa0 = mfma16(qf1, ld8any(pr0 + 32),      pa0);
      const bf16* pr1 = pr0 + 32 * HD;
      pa1 = mfma16(qf0, ld8any(pr1),           pa1);
      pa1 = mfma16(qf1, ld8any(pr1 + 32),      pa1);
    }
#pragma unroll
    for (int r = 0; r < 4; ++r) {
      cont_lds[wr + r][wsel*16 + col16]      = ca0[r];
      cont_lds[wr + r][wsel*16 + 32 + col16] = ca1[r];
      cont_lds[wr + r][wsel*16 + 64 + col16] = ca2[r];
      pos_lds[wr + r][wsel*16 + col16]       = pa0[r];
      pos_lds[wr + r][wsel*16 + 32 + col16]  = pa1[r];
    }
    __syncthreads();

    // ---- phase 2: combine + online softmax (s[m][l] = cont[m][m+l]+pos[m][l]) ----
    float sc[8];
    float mc = -1.0e30f;
    const float* crow = &cont_lds[srow][srow + sj*8];
    const float* prow = &pos_lds[srow][sj*8];
#pragma unroll
    for (int i = 0; i < 8; ++i) {
      float v = (crow[i] + prow[i]) * 0.125f;
      sc[i] = v;
      mc = fmaxf(mc, v);
    }
    mc = fmaxf(mc, __shfl_xor(mc, 1));
    mc = fmaxf(mc, __shfl_xor(mc, 2));
    mc = fmaxf(mc, __shfl_xor(mc, 4));
    const float Mnew = fmaxf(Mrun, mc);
    const float alpha = __expf(Mrun - Mnew);   // finite args; chunk 0 -> 0
    float ls = 0.0f;
    bf16* pwrow = &P_lds[srow][srow + sj*8];
#pragma unroll
    for (int i = 0; i < 8; ++i) {
      float p = __expf(sc[i] - Mnew);
      ls += p;
      // adaptive-span soft mask (post-softmax numerator; S stays unmasked)
      const float tpl = (float)(l0 + sj*8 + i) - 1023.0f;
      float mv = (tpl + span * 1024.0f) * 0.03125f + 1.0f;
      mv = fminf(fmaxf(mv, 0.0f), 1.0f);
      pwrow[i] = __float2bfloat16(p * mv);
    }
    ls += __shfl_xor(ls, 1);
    ls += __shfl_xor(ls, 2);
    ls += __shfl_xor(ls, 4);
    Srun = Srun * alpha + ls;
    Mrun = Mnew;
    if (sj == 0) { alpha_lds[srow] = alpha; S_lds[srow] = Srun; }
    __syncthreads();

    // ---- phase 3: rescale O, PV MFMA over the 96-key span ----
    float al[4];
#pragma unroll
    for (int r = 0; r < 4; ++r) al[r] = alpha_lds[wr + r];
#pragma unroll
    for (int r = 0; r < 4; ++r) { o0[r] *= al[r]; o1[r] *= al[r]; }
#pragma unroll
    for (int ks = 0; ks < 3; ++ks) {
      const bf16x8 ap = ld8any(&P_lds[msub*16 + col16][ks*32 + kq]);
      const bf16* v0 = vb + (size_t)(dt0 + col16) * SN + nb_ + ks*32 + kq;
      const bf16* v1 = vb + (size_t)(dt1 + col16) * SN + nb_ + ks*32 + kq;
      o0 = mfma16(ap, ld8any(v0), o0);
      o1 = mfma16(ap, ld8any(v1), o1);
    }
    __syncthreads();   // paranoia barrier; revisit once passing
  }

  // ---- epilogue: O / S -> ctx[b*512 + m][h*64+d] (bf16) ----
  bf16* cr = ctx + (size_t)(b*SM + m0 + wr) * SH + h*HD + col16;
#pragma unroll
  for (int r = 0; r < 4; ++r) {
    const float inv = 1.0f / S_lds[wr + r];
    cr[(size_t)r * SH + dt0] = __float2bfloat16(o0[r] * inv);
    cr[(size_t)r * SH + dt1] = __float2bfloat16(o1[r] * inv);
  }
}

// ---------------------------------------------------------------------------
extern "C" void kernel_launch(void* const* d_in, const int* in_sizes, int n_in,
                              void* d_out, int out_size, void* d_ws, size_t ws_size,
                              hipStream_t stream) {
  const float* query  = (const float*)d_in[0];   // [8, 512, 512]
  const float* key    = (const float*)d_in[1];   // [8, 1536, 512]
  const float* value  = (const float*)d_in[2];   // [8, 1536, 512]
  const float* key_pe = (const float*)d_in[3];   // [1, 64, 1024]
  const float* Wq     = (const float*)d_in[4];   // [512, 512]
  const float* Wk     = (const float*)d_in[5];
  const float* Wv     = (const float*)d_in[6];
  const float* Wo     = (const float*)d_in[7];
  const float* spanv  = (const float*)d_in[8];   // [8]
  float* out = (float*)d_out;

  bf16* ws = (bf16*)d_ws;
  if (ws_size >= (size_t)29491200) {
    // Full-batch pipeline: 5 dispatches, 29.5 MB ws.
    bf16* k_proj = ws;                    // [8*1536, 512]
    bf16* vT     = k_proj + 6291456;      // [64*64, 1536]
    bf16* ctx    = vT     + 6291456;      // [8*512, 512]
    bf16* peT    = ctx    + 2097152;      // [1024, 64]
    gemm_bt<float,float,bf16><<<dim3(192, 8), 256, 0, stream>>>(key, Wk, k_proj);
    gemm_v_t<<<dim3(192, 8), 256, 0, stream>>>(value, Wv, vT);
    transpose_pe<<<256, 256, 0, stream>>>(key_pe, peT);
    attn_kernel<<<dim3(16, 64), 256, 0, stream>>>(query, Wq, k_proj, vT, peT,
                                                  spanv, ctx);
    gemm_bt<bf16,float,float><<<dim3(64, 8), 256, 0, stream>>>(ctx, Wo, out);
  } else {
    // Per-batch-sliced fallback: 3.8 MB ws, 33 dispatches.
    bf16* k_proj = ws;                    // [1536, 512]
    bf16* vT     = k_proj + 786432;       // [8*64, 1536]
    bf16* ctx    = vT     + 786432;       // [512, 512]
    bf16* peT    = ctx    + 262144;       // [1024, 64]
    transpose_pe<<<256, 256, 0, stream>>>(key_pe, peT);
    for (int b = 0; b < NB; ++b) {
      const float* key_b   = key   + (size_t)b * SN * SH;
      const float* value_b = value + (size_t)b * SN * SH;
      const float* query_b = query + (size_t)b * SM * SH;
      float*       out_b   = out   + (size_t)b * SM * SH;
      gemm_bt<float,float,bf16><<<dim3(24, 8), 256, 0, stream>>>(key_b, Wk, k_proj);
      gemm_v_t<<<dim3(24, 8), 256, 0, stream>>>(value_b, Wv, vT);
      attn_kernel<<<dim3(16, 8), 256, 0, stream>>>(query_b, Wq, k_proj, vT, peT,
                                                   spanv, ctx);
      gemm_bt<bf16,float,float><<<dim3(8, 8), 256, 0, stream>>>(ctx, Wo, out_b);
    }
  }
}

// Round 5
// 412.096 us; speedup vs baseline: 1.2307x; 1.2307x over previous
//
#include <hip/hip_runtime.h>
#include <hip/hip_bf16.h>

typedef __hip_bfloat16 bf16;
typedef short bf16x8 __attribute__((ext_vector_type(8)));
typedef float f32x4 __attribute__((ext_vector_type(4)));

#define NB 8      // batch
#define SM 512    // block size M
#define SL 1024   // attn span L
#define SH 512    // hidden
#define NH 8      // heads
#define HD 64     // head dim
#define SN 1536   // M + L (key length)

static __device__ __forceinline__ short bf_bits(float x) {
  union { bf16 b; short s; } u; u.b = __float2bfloat16(x); return u.s;
}
static __device__ __forceinline__ bf16x8 ld8any(const bf16* p) {
  return *reinterpret_cast<const bf16x8*>(p);
}
static __device__ __forceinline__ bf16x8 ld8any(const float* p) {
  float4 a = *reinterpret_cast<const float4*>(p);
  float4 b = *reinterpret_cast<const float4*>(p + 4);
  bf16x8 r;
  r[0] = bf_bits(a.x); r[1] = bf_bits(a.y); r[2] = bf_bits(a.z); r[3] = bf_bits(a.w);
  r[4] = bf_bits(b.x); r[5] = bf_bits(b.y); r[6] = bf_bits(b.z); r[7] = bf_bits(b.w);
  return r;
}
static __device__ __forceinline__ void st1(bf16* p, float v) { *p = __float2bfloat16(v); }
static __device__ __forceinline__ void st1(float* p, float v) { *p = v; }
static __device__ __forceinline__ f32x4 mfma16(bf16x8 a, bf16x8 b, f32x4 c) {
  return __builtin_amdgcn_mfma_f32_16x16x32_bf16(a, b, c, 0, 0, 0);
}

// ---------------------------------------------------------------------------
// Y[R x 512] = X[R x 512] @ W^T, 128x128 block tile, XCD-swizzled 1-D grid.
// grid = (R/128)*4 blocks; decode: id = xcd + 8*(y + 4*xhi), xblk = xcd+8*xhi.
// All 4 y-columns of an xblk land on one XCD -> X-slice read once per XCD.
// MODE 0: Y[row][col] plain row-major.
// MODE 1: k_head layout Y[((b*8+h)*1536 + s)*64 + d]   (b=row/1536, h=col/64)
// MODE 2: vT layout     Y[((b*8+h)*64 + d)*1536 + s]
// ---------------------------------------------------------------------------
template <int MODE, typename TX, typename TW, typename TY>
__global__ __launch_bounds__(256) void gemm128(const TX* __restrict__ X,
                                               const TW* __restrict__ W,
                                               TY* __restrict__ Y) {
  const int id   = blockIdx.x;
  const int s_   = id >> 3;
  const int xblk = (id & 7) + 8 * (s_ >> 2);
  const int yblk = s_ & 3;
  const int tid  = threadIdx.x;
  const int lane = tid & 63, wave = tid >> 6;
  const int col16 = lane & 15, quad = lane >> 4, kq = quad << 3;
  const int m0 = xblk * 128 + (wave >> 1) * 64;
  const int n0 = yblk * 128 + (wave & 1) * 64;
  const TX* xr = X + (size_t)(m0 + col16) * SH + kq;
  const TW* wr = W + (size_t)(n0 + col16) * SH + kq;
  f32x4 acc[4][4];
#pragma unroll
  for (int i = 0; i < 4; ++i)
#pragma unroll
    for (int j = 0; j < 4; ++j) acc[i][j] = f32x4{0.f,0.f,0.f,0.f};
#pragma unroll
  for (int k0 = 0; k0 < SH; k0 += 32) {
    bf16x8 af[4], bfr[4];
#pragma unroll
    for (int t = 0; t < 4; ++t) af[t]  = ld8any(xr + (size_t)(t*16) * SH + k0);
#pragma unroll
    for (int t = 0; t < 4; ++t) bfr[t] = ld8any(wr + (size_t)(t*16) * SH + k0);
#pragma unroll
    for (int mt = 0; mt < 4; ++mt)
#pragma unroll
      for (int nt = 0; nt < 4; ++nt)
        acc[mt][nt] = mfma16(af[mt], bfr[nt], acc[mt][nt]);
  }
#pragma unroll
  for (int mt = 0; mt < 4; ++mt) {
#pragma unroll
    for (int r = 0; r < 4; ++r) {
      const int row = m0 + mt*16 + quad*4 + r;
      if constexpr (MODE == 0) {
        TY* yr = Y + (size_t)row * SH + n0 + col16;
#pragma unroll
        for (int nt = 0; nt < 4; ++nt) st1(yr + nt*16, acc[mt][nt][r]);
      } else {
        const int b = row / SN, sr = row - b * SN;
#pragma unroll
        for (int nt = 0; nt < 4; ++nt) {
          const int col = n0 + nt*16 + col16;
          const int h = col >> 6, d = col & 63;
          if constexpr (MODE == 1)
            Y[(size_t)((b*NH + h)*SN + sr) * HD + d] = __float2bfloat16(acc[mt][nt][r]);
          else
            Y[(size_t)((b*NH + h)*HD + d) * SN + sr] = __float2bfloat16(acc[mt][nt][r]);
        }
      }
    }
  }
}

// ---------------------------------------------------------------------------
// peT[l][d] = bf16(pe[d][l])    (64 x 1024 f32 -> 1024 x 64 bf16)
// ---------------------------------------------------------------------------
__global__ void transpose_pe(const float* __restrict__ pe, bf16* __restrict__ peT) {
  int idx = blockIdx.x * 256 + threadIdx.x;     // 65536 total
  int l = idx >> 6, d = idx & 63;
  peT[idx] = __float2bfloat16(pe[d * SL + l]);
}

// ---------------------------------------------------------------------------
// Sliding-window attention, flash-style online softmax, XCD-swizzled:
// 1-D grid 1024; id = h + 8*(mtile + 16*b) -> all blocks of head h on XCD h.
// K in per-head layout [hb][n][64]; FUSEDQ=1 projects q in-kernel (fallback).
// ---------------------------------------------------------------------------
#define MT 32
#define CSTR 100   // cont_lds f32 row stride (96 + pad)
#define PSTR 65    // pos_lds  f32 row stride (64 + pad; 65 -> 2-way max)
#define BSTR 104   // P_lds bf16 row stride (96 + pad, 16B-multiple rows)
#define QSTR 72    // q_lds bf16 row stride (64 + pad, 16B-multiple rows)

template <int FUSEDQ>
__global__ __launch_bounds__(256) void attn_kernel(
    const float* __restrict__ query, const float* __restrict__ Wq,
    const bf16* __restrict__ qp,
    const bf16* __restrict__ Kh, const bf16* __restrict__ VT,
    const bf16* __restrict__ peT, const float* __restrict__ spanv,
    bf16* __restrict__ ctx) {
  __shared__ __align__(16) float cont_lds[MT][CSTR];
  __shared__ __align__(16) float pos_lds[MT][PSTR];
  __shared__ __align__(16) bf16  P_lds[MT][BSTR];
  __shared__ __align__(16) bf16  q_lds[FUSEDQ ? MT*QSTR : 8];
  __shared__ float alpha_lds[MT];
  __shared__ float S_lds[MT];

  const int id = blockIdx.x;
  const int h  = id & 7;
  const int s_ = id >> 3;
  const int m0 = (s_ & 15) * MT;
  const int b  = s_ >> 4;
  const int hb = b * 8 + h;
  const int tid  = threadIdx.x;
  const int lane = tid & 63;
  const int wave = tid >> 6;
  const int col16 = lane & 15, quad = lane >> 4, kq = quad << 3;
  const int msub = wave & 1;    // 16-row half
  const int wsel = wave >> 1;   // tile interleave selector
  const int wr = msub*16 + (quad << 2);

  // zero P band tile once (band cell positions are chunk-invariant)
  for (int i = tid; i < MT * BSTR; i += 256)
    (&P_lds[0][0])[i] = __float2bfloat16(0.0f);

  bf16x8 qf0, qf1;
  if constexpr (FUSEDQ) {
    // fused Q projection: q_lds[32][64] = query_tile @ Wq[h*64.., :]^T
    f32x4 qa0 = {0.f,0.f,0.f,0.f}, qa1 = qa0;
    const float* xq = query + (size_t)(b*SM + m0 + msub*16 + col16) * SH + kq;
    const float* w0 = Wq + (size_t)(h*HD + wsel*32 + col16) * SH + kq;
    const float* w1 = w0 + (size_t)16 * SH;
#pragma unroll
    for (int k0 = 0; k0 < SH; k0 += 32) {
      bf16x8 xa = ld8any(xq + k0);
      qa0 = mfma16(xa, ld8any(w0 + k0), qa0);
      qa1 = mfma16(xa, ld8any(w1 + k0), qa1);
    }
#pragma unroll
    for (int r = 0; r < 4; ++r) {
      q_lds[(wr + r)*QSTR + wsel*32 + col16]      = __float2bfloat16(qa0[r]);
      q_lds[(wr + r)*QSTR + wsel*32 + 16 + col16] = __float2bfloat16(qa1[r]);
    }
    __syncthreads();
    qf0 = ld8any(&q_lds[(msub*16 + col16)*QSTR + kq]);
    qf1 = ld8any(&q_lds[(msub*16 + col16)*QSTR + kq + 32]);
  } else {
    const bf16* qb = qp + (size_t)(b*SM + m0 + msub*16 + col16) * SH + h*HD + kq;
    qf0 = ld8any(qb);
    qf1 = ld8any(qb + 32);
  }

  const bf16* kb = Kh + (size_t)(hb * SN) * HD + kq;   // per-head K rows, 128B
  const bf16* vb = VT + (size_t)(hb * HD) * SN;

  const int srow = tid >> 3, sj = tid & 7;   // softmax: 8 threads per row
  float Mrun = -1.0e30f, Srun = 0.0f;
  const float span = spanv[h];
  const int dt0 = wsel * 16, dt1 = (wsel + 2) * 16;
  f32x4 o0 = {0.f,0.f,0.f,0.f}, o1 = o0;

  for (int ch = 0; ch < 16; ++ch) {
    const int l0 = ch << 6;
    const int nb_ = m0 + l0;   // absolute key base; max 1440, +95 < 1536

    // ---- phase 1: MFMA cont (3 n-tiles) + pos (2 l-tiles) -> LDS ----
    f32x4 ca0 = {0.f,0.f,0.f,0.f}, ca1 = ca0, ca2 = ca0, pa0 = ca0, pa1 = ca0;
    {
      const bf16* kr0 = kb + (size_t)(nb_ + wsel*16 + col16) * HD;
      ca0 = mfma16(qf0, ld8any(kr0),           ca0);
      ca0 = mfma16(qf1, ld8any(kr0 + 32),      ca0);
      const bf16* kr1 = kr0 + 32 * HD;
      ca1 = mfma16(qf0, ld8any(kr1),           ca1);
      ca1 = mfma16(qf1, ld8any(kr1 + 32),      ca1);
      const bf16* kr2 = kr0 + 64 * HD;
      ca2 = mfma16(qf0, ld8any(kr2),           ca2);
      ca2 = mfma16(qf1, ld8any(kr2 + 32),      ca2);
      const bf16* pr0 = peT + (size_t)(l0 + wsel*16 + col16) * HD + kq;
      pa0 = mfma16(qf0, ld8any(pr0),           pa0);
      pa0 = mfma16(qf1, ld8any(pr0 + 32),      pa0);
      const bf16* pr1 = pr0 + 32 * HD;
      pa1 = mfma16(qf0, ld8any(pr1),           pa1);
      pa1 = mfma16(qf1, ld8any(pr1 + 32),      pa1);
    }
#pragma unroll
    for (int r = 0; r < 4; ++r) {
      cont_lds[wr + r][wsel*16 + col16]      = ca0[r];
      cont_lds[wr + r][wsel*16 + 32 + col16] = ca1[r];
      cont_lds[wr + r][wsel*16 + 64 + col16] = ca2[r];
      pos_lds[wr + r][wsel*16 + col16]       = pa0[r];
      pos_lds[wr + r][wsel*16 + 32 + col16]  = pa1[r];
    }
    __syncthreads();

    // ---- phase 2: combine + online softmax (s[m][l] = cont[m][m+l]+pos[m][l]) ----
    float sc[8];
    float mc = -1.0e30f;
    const float* crow = &cont_lds[srow][srow + sj*8];
    const float* prow = &pos_lds[srow][sj*8];
#pragma unroll
    for (int i = 0; i < 8; ++i) {
      float v = (crow[i] + prow[i]) * 0.125f;
      sc[i] = v;
      mc = fmaxf(mc, v);
    }
    mc = fmaxf(mc, __shfl_xor(mc, 1));
    mc = fmaxf(mc, __shfl_xor(mc, 2));
    mc = fmaxf(mc, __shfl_xor(mc, 4));
    const float Mnew = fmaxf(Mrun, mc);
    const float alpha = __expf(Mrun - Mnew);   // finite args; chunk 0 -> 0
    float ls = 0.0f;
    bf16* pwrow = &P_lds[srow][srow + sj*8];
#pragma unroll
    for (int i = 0; i < 8; ++i) {
      float p = __expf(sc[i] - Mnew);
      ls += p;
      // adaptive-span soft mask (post-softmax numerator; S stays unmasked)
      const float tpl = (float)(l0 + sj*8 + i) - 1023.0f;
      float mv = (tpl + span * 1024.0f) * 0.03125f + 1.0f;
      mv = fminf(fmaxf(mv, 0.0f), 1.0f);
      pwrow[i] = __float2bfloat16(p * mv);
    }
    ls += __shfl_xor(ls, 1);
    ls += __shfl_xor(ls, 2);
    ls += __shfl_xor(ls, 4);
    Srun = Srun * alpha + ls;
    Mrun = Mnew;
    if (sj == 0) { alpha_lds[srow] = alpha; S_lds[srow] = Srun; }
    __syncthreads();

    // ---- phase 3: rescale O, PV MFMA over the 96-key span ----
    // (no barrier after: next phase-1 writes cont/pos only; P_lds next written
    //  in next phase 2, which is after the next phase-1 barrier.)
    float al[4];
#pragma unroll
    for (int r = 0; r < 4; ++r) al[r] = alpha_lds[wr + r];
#pragma unroll
    for (int r = 0; r < 4; ++r) { o0[r] *= al[r]; o1[r] *= al[r]; }
#pragma unroll
    for (int ks = 0; ks < 3; ++ks) {
      const bf16x8 ap = ld8any(&P_lds[msub*16 + col16][ks*32 + kq]);
      const bf16* v0 = vb + (size_t)(dt0 + col16) * SN + nb_ + ks*32 + kq;
      const bf16* v1 = vb + (size_t)(dt1 + col16) * SN + nb_ + ks*32 + kq;
      o0 = mfma16(ap, ld8any(v0), o0);
      o1 = mfma16(ap, ld8any(v1), o1);
    }
  }

  // ---- epilogue: O / S -> ctx[b*512 + m][h*64+d] (bf16) ----
  bf16* cr = ctx + (size_t)(b*SM + m0 + wr) * SH + h*HD + col16;
#pragma unroll
  for (int r = 0; r < 4; ++r) {
    const float inv = 1.0f / S_lds[wr + r];
    cr[(size_t)r * SH + dt0] = __float2bfloat16(o0[r] * inv);
    cr[(size_t)r * SH + dt1] = __float2bfloat16(o1[r] * inv);
  }
}

// ---------------------------------------------------------------------------
extern "C" void kernel_launch(void* const* d_in, const int* in_sizes, int n_in,
                              void* d_out, int out_size, void* d_ws, size_t ws_size,
                              hipStream_t stream) {
  const float* query  = (const float*)d_in[0];   // [8, 512, 512]
  const float* key    = (const float*)d_in[1];   // [8, 1536, 512]
  const float* value  = (const float*)d_in[2];   // [8, 1536, 512]
  const float* key_pe = (const float*)d_in[3];   // [1, 64, 1024]
  const float* Wq     = (const float*)d_in[4];   // [512, 512]
  const float* Wk     = (const float*)d_in[5];
  const float* Wv     = (const float*)d_in[6];
  const float* Wo     = (const float*)d_in[7];
  const float* spanv  = (const float*)d_in[8];   // [8]
  float* out = (float*)d_out;

  bf16* ws = (bf16*)d_ws;
  if (ws_size >= (size_t)33685504) {
    // Path A: precomputed q_proj. 6 dispatches, 33.7 MB ws.
    bf16* k_head = ws;                    // [64*1536, 64]
    bf16* vT     = k_head + 6291456;      // [64*64, 1536]
    bf16* ctx    = vT     + 6291456;      // [8*512, 512]
    bf16* qp     = ctx    + 2097152;      // [8*512, 512]
    bf16* peT    = qp     + 2097152;      // [1024, 64]
    gemm128<1, float, float, bf16><<<384, 256, 0, stream>>>(key,   Wk, k_head);
    gemm128<2, float, float, bf16><<<384, 256, 0, stream>>>(value, Wv, vT);
    gemm128<0, float, float, bf16><<<128, 256, 0, stream>>>(query, Wq, qp);
    transpose_pe<<<256, 256, 0, stream>>>(key_pe, peT);
    attn_kernel<0><<<1024, 256, 0, stream>>>(nullptr, nullptr, qp, k_head, vT,
                                             peT, spanv, ctx);
    gemm128<0, bf16, float, float><<<128, 256, 0, stream>>>(ctx, Wo, out);
  } else {
    // Path B: fused-q attention. 5 dispatches, 29.5 MB ws (proven to fit).
    bf16* k_head = ws;                    // [64*1536, 64]
    bf16* vT     = k_head + 6291456;      // [64*64, 1536]
    bf16* ctx    = vT     + 6291456;      // [8*512, 512]
    bf16* peT    = ctx    + 2097152;      // [1024, 64]
    gemm128<1, float, float, bf16><<<384, 256, 0, stream>>>(key,   Wk, k_head);
    gemm128<2, float, float, bf16><<<384, 256, 0, stream>>>(value, Wv, vT);
    transpose_pe<<<256, 256, 0, stream>>>(key_pe, peT);
    attn_kernel<1><<<1024, 256, 0, stream>>>(query, Wq, nullptr, k_head, vT,
                                             peT, spanv, ctx);
    gemm128<0, bf16, float, float><<<128, 256, 0, stream>>>(ctx, Wo, out);
  }
}

// Round 6
// 397.801 us; speedup vs baseline: 1.2750x; 1.0359x over previous
//
#include <hip/hip_runtime.h>
#include <hip/hip_bf16.h>
#include <type_traits>

typedef __hip_bfloat16 bf16;
typedef short bf16x8 __attribute__((ext_vector_type(8)));
typedef float f32x4 __attribute__((ext_vector_type(4)));

#define NB 8      // batch
#define SM 512    // block size M
#define SL 1024   // attn span L
#define SH 512    // hidden
#define NH 8      // heads
#define HD 64     // head dim
#define SN 1536   // M + L (key length)

static __device__ __forceinline__ short bf_bits(float x) {
  union { bf16 b; short s; } u; u.b = __float2bfloat16(x); return u.s;
}
static __device__ __forceinline__ bf16x8 ld8any(const bf16* p) {
  return *reinterpret_cast<const bf16x8*>(p);
}
static __device__ __forceinline__ bf16x8 ld8any(const float* p) {
  float4 a = *reinterpret_cast<const float4*>(p);
  float4 b = *reinterpret_cast<const float4*>(p + 4);
  bf16x8 r;
  r[0] = bf_bits(a.x); r[1] = bf_bits(a.y); r[2] = bf_bits(a.z); r[3] = bf_bits(a.w);
  r[4] = bf_bits(b.x); r[5] = bf_bits(b.y); r[6] = bf_bits(b.z); r[7] = bf_bits(b.w);
  return r;
}
static __device__ __forceinline__ f32x4 mfma16(bf16x8 a, bf16x8 b, f32x4 c) {
  return __builtin_amdgcn_mfma_f32_16x16x32_bf16(a, b, c, 0, 0, 0);
}

// ---------------------------------------------------------------------------
// Y[R x 512] = X[R x 512] @ W^T, 128x128 tile, XCD-swizzled 1-D grid.
// id = xcd + 8*(y + 4*xhi); xblk = xcd + 8*xhi; all 4 y-cols of an xblk on
// one XCD. Epilogue: LDS-staged -> 128B contiguous stores (except f32 MODE 0).
// MODE 0: Y[row][col] row-major.
// MODE 1: k_head  Y[((b*8+h)*1536 + s)*64 + d]
// MODE 2: vT      Y[((b*8+h)*64 + d)*1536 + s]   (staged transposed)
// ---------------------------------------------------------------------------
#define TSTR 136

template <int MODE, typename TX, typename TW, typename TY>
__global__ __launch_bounds__(256) void gemm128(const TX* __restrict__ X,
                                               const TW* __restrict__ W,
                                               TY* __restrict__ Y) {
  constexpr bool DIRECT = (MODE == 0 && std::is_same<TY, float>::value);
  __shared__ __align__(16) bf16 tile[DIRECT ? 8 : 128 * TSTR];
  const int id   = blockIdx.x;
  const int s_   = id >> 3;
  const int xblk = (id & 7) + 8 * (s_ >> 2);
  const int yblk = s_ & 3;
  const int tid  = threadIdx.x;
  const int lane = tid & 63, wave = tid >> 6;
  const int col16 = lane & 15, quad = lane >> 4, kq = quad << 3;
  const int m0 = xblk * 128 + (wave >> 1) * 64;
  const int n0 = yblk * 128 + (wave & 1) * 64;
  const TX* xr = X + (size_t)(m0 + col16) * SH + kq;
  const TW* wr = W + (size_t)(n0 + col16) * SH + kq;
  f32x4 acc[4][4];
#pragma unroll
  for (int i = 0; i < 4; ++i)
#pragma unroll
    for (int j = 0; j < 4; ++j) acc[i][j] = f32x4{0.f,0.f,0.f,0.f};
#pragma unroll
  for (int k0 = 0; k0 < SH; k0 += 32) {
    bf16x8 af[4], bfr[4];
#pragma unroll
    for (int t = 0; t < 4; ++t) af[t]  = ld8any(xr + (size_t)(t*16) * SH + k0);
#pragma unroll
    for (int t = 0; t < 4; ++t) bfr[t] = ld8any(wr + (size_t)(t*16) * SH + k0);
#pragma unroll
    for (int mt = 0; mt < 4; ++mt)
#pragma unroll
      for (int nt = 0; nt < 4; ++nt)
        acc[mt][nt] = mfma16(af[mt], bfr[nt], acc[mt][nt]);
  }

  if constexpr (DIRECT) {
#pragma unroll
    for (int mt = 0; mt < 4; ++mt)
#pragma unroll
      for (int r = 0; r < 4; ++r) {
        const int row = m0 + mt*16 + quad*4 + r;
        float* yr = (float*)Y + (size_t)row * SH + n0 + col16;
#pragma unroll
        for (int nt = 0; nt < 4; ++nt) yr[nt*16] = acc[mt][nt][r];
      }
  } else {
#pragma unroll
    for (int mt = 0; mt < 4; ++mt)
#pragma unroll
      for (int r = 0; r < 4; ++r) {
        const int row_loc = (wave >> 1)*64 + mt*16 + quad*4 + r;
#pragma unroll
        for (int nt = 0; nt < 4; ++nt) {
          const int col_loc = (wave & 1)*64 + nt*16 + col16;
          if constexpr (MODE == 2)
            tile[col_loc * TSTR + row_loc] = __float2bfloat16(acc[mt][nt][r]);
          else
            tile[row_loc * TSTR + col_loc] = __float2bfloat16(acc[mt][nt][r]);
        }
      }
    __syncthreads();
    const int a  = tid >> 1;    // 0..127
    const int hh = tid & 1;     // 0/1
    const bf16* src = tile + a * TSTR + hh * 64;
    bf16* dst;
    if constexpr (MODE == 0) {
      const int row = xblk*128 + a;
      dst = (bf16*)Y + (size_t)row * SH + yblk*128 + hh*64;
    } else if constexpr (MODE == 1) {
      const int row = xblk*128 + a;
      const int b = row / SN, sr = row - b * SN;
      const int col0 = yblk*128 + hh*64;
      const int h = col0 >> 6;
      dst = (bf16*)Y + (size_t)((b*NH + h)*SN + sr) * HD;
    } else {
      const int col = yblk*128 + a;
      const int h = col >> 6, d = col & 63;
      const int row0 = xblk*128 + hh*64;
      const int b = row0 / SN, sr0 = row0 - b * SN;
      dst = (bf16*)Y + (size_t)((b*NH + h)*HD + d) * SN + sr0;
    }
#pragma unroll
    for (int i = 0; i < 8; ++i)
      reinterpret_cast<uint4*>(dst)[i] = reinterpret_cast<const uint4*>(src)[i];
  }
}

// ---------------------------------------------------------------------------
// peT[l][d] = bf16(pe[d][l])    (64 x 1024 f32 -> 1024 x 64 bf16)
// ---------------------------------------------------------------------------
__global__ void transpose_pe(const float* __restrict__ pe, bf16* __restrict__ peT) {
  int idx = blockIdx.x * 256 + threadIdx.x;     // 65536 total
  int l = idx >> 6, d = idx & 63;
  peT[idx] = __float2bfloat16(pe[d * SL + l]);
}

// ---------------------------------------------------------------------------
// Sliding-window attention, flash-style, 16 query rows/block, 2 waves.
// 1-D grid 2048; id = h + 8*(mtile + 32*b) -> all blocks of head h on XCD h.
// ---------------------------------------------------------------------------
#define MT 16
#define CSTR 84    // cont_lds f32 row stride (80 + pad)
#define PSTR 65    // pos_lds  f32 row stride (64 + pad)
#define BSTR 104   // P_lds bf16 row stride (96 + pad, 16B-multiple rows)
#define QSTR 72    // q_lds bf16 row stride (FUSEDQ only)

template <int FUSEDQ>
__global__ __launch_bounds__(128) void attn_kernel(
    const float* __restrict__ query, const float* __restrict__ Wq,
    const bf16* __restrict__ qp,
    const bf16* __restrict__ Kh, const bf16* __restrict__ VT,
    const bf16* __restrict__ peT, const float* __restrict__ spanv,
    bf16* __restrict__ ctx) {
  __shared__ __align__(16) float cont_lds[MT][CSTR];
  __shared__ __align__(16) float pos_lds[MT][PSTR];
  __shared__ __align__(16) bf16  P_lds[MT][BSTR];
  __shared__ __align__(16) bf16  q_lds[FUSEDQ ? MT*QSTR : 8];
  __shared__ float alpha_lds[MT];
  __shared__ float S_lds[MT];

  const int id = blockIdx.x;
  const int h  = id & 7;
  const int s_ = id >> 3;
  const int m0 = (s_ & 31) * MT;
  const int b  = s_ >> 5;
  const int hb = b * 8 + h;
  const int tid  = threadIdx.x;
  const int lane = tid & 63;
  const int w    = tid >> 6;          // wave 0/1
  const int col16 = lane & 15, quad = lane >> 4, kq = quad << 3;
  const int wr = quad << 2;           // acc row base (rows 0..15)

  // zero P band tile once (band cell positions are chunk-invariant)
  for (int i = tid; i < MT * BSTR; i += 128)
    (&P_lds[0][0])[i] = __float2bfloat16(0.0f);

  bf16x8 qf0, qf1;
  if constexpr (FUSEDQ) {
    f32x4 qa0 = {0.f,0.f,0.f,0.f}, qa1 = qa0;
    const float* xq = query + (size_t)(b*SM + m0 + col16) * SH + kq;
    const float* w0 = Wq + (size_t)(h*HD + w*32 + col16) * SH + kq;
    const float* w1 = w0 + (size_t)16 * SH;
#pragma unroll
    for (int k0 = 0; k0 < SH; k0 += 32) {
      bf16x8 xa = ld8any(xq + k0);
      qa0 = mfma16(xa, ld8any(w0 + k0), qa0);
      qa1 = mfma16(xa, ld8any(w1 + k0), qa1);
    }
#pragma unroll
    for (int r = 0; r < 4; ++r) {
      q_lds[(wr + r)*QSTR + w*32 + col16]      = __float2bfloat16(qa0[r]);
      q_lds[(wr + r)*QSTR + w*32 + 16 + col16] = __float2bfloat16(qa1[r]);
    }
    __syncthreads();
    qf0 = ld8any(&q_lds[col16*QSTR + kq]);
    qf1 = ld8any(&q_lds[col16*QSTR + kq + 32]);
  } else {
    const bf16* qb = qp + (size_t)(b*SM + m0 + col16) * SH + h*HD + kq;
    qf0 = ld8any(qb);
    qf1 = ld8any(qb + 32);
  }

  const bf16* kb = Kh + (size_t)(hb * SN) * HD + kq;   // per-head K rows, 128B
  const bf16* vb = VT + (size_t)(hb * HD) * SN;

  const int srow = tid >> 3, sj = tid & 7;   // softmax: 16 rows x 8 threads
  float Mrun = -1.0e30f, Srun = 0.0f;
  const float span = spanv[h];
  const int dt0 = w * 16, dt1 = (w + 2) * 16;
  f32x4 o0 = {0.f,0.f,0.f,0.f}, o1 = o0;

  for (int ch = 0; ch < 16; ++ch) {
    const int l0 = ch << 6;
    const int nb_ = m0 + l0;   // absolute key base; max 496+960; +79 < 1536

    // ---- phase 1: cont tiles (span 80: w0 -> {0,32,64}, w1 -> {16,48}),
    //               pos tiles (w*16 + {0,32}) -> LDS ----
    f32x4 ca0 = {0.f,0.f,0.f,0.f}, ca1 = ca0, ca2 = ca0, pa0 = ca0, pa1 = ca0;
    {
      const bf16* kr0 = kb + (size_t)(nb_ + w*16 + col16) * HD;
      ca0 = mfma16(qf0, ld8any(kr0),           ca0);
      ca0 = mfma16(qf1, ld8any(kr0 + 32),      ca0);
      const bf16* kr1 = kr0 + 32 * HD;
      ca1 = mfma16(qf0, ld8any(kr1),           ca1);
      ca1 = mfma16(qf1, ld8any(kr1 + 32),      ca1);
      if (w == 0) {
        const bf16* kr2 = kr0 + 64 * HD;
        ca2 = mfma16(qf0, ld8any(kr2),         ca2);
        ca2 = mfma16(qf1, ld8any(kr2 + 32),    ca2);
      }
      const bf16* pr0 = peT + (size_t)(l0 + w*16 + col16) * HD + kq;
      pa0 = mfma16(qf0, ld8any(pr0),           pa0);
      pa0 = mfma16(qf1, ld8any(pr0 + 32),      pa0);
      const bf16* pr1 = pr0 + 32 * HD;
      pa1 = mfma16(qf0, ld8any(pr1),           pa1);
      pa1 = mfma16(qf1, ld8any(pr1 + 32),      pa1);
    }
#pragma unroll
    for (int r = 0; r < 4; ++r) {
      cont_lds[wr + r][w*16 + col16]      = ca0[r];
      cont_lds[wr + r][w*16 + 32 + col16] = ca1[r];
      if (w == 0) cont_lds[wr + r][64 + col16] = ca2[r];
      pos_lds[wr + r][w*16 + col16]       = pa0[r];
      pos_lds[wr + r][w*16 + 32 + col16]  = pa1[r];
    }
    __syncthreads();

    // ---- phase 2: combine + online softmax (s[m][l] = cont[m][m+l]+pos[m][l]) ----
    float sc[8];
    float mc = -1.0e30f;
    const float* crow = &cont_lds[srow][srow + sj*8];
    const float* prow = &pos_lds[srow][sj*8];
#pragma unroll
    for (int i = 0; i < 8; ++i) {
      float v = (crow[i] + prow[i]) * 0.125f;
      sc[i] = v;
      mc = fmaxf(mc, v);
    }
    mc = fmaxf(mc, __shfl_xor(mc, 1));
    mc = fmaxf(mc, __shfl_xor(mc, 2));
    mc = fmaxf(mc, __shfl_xor(mc, 4));
    const float Mnew = fmaxf(Mrun, mc);
    const float alpha = __expf(Mrun - Mnew);   // finite args; chunk 0 -> 0
    float ls = 0.0f;
    bf16* pwrow = &P_lds[srow][srow + sj*8];
#pragma unroll
    for (int i = 0; i < 8; ++i) {
      float p = __expf(sc[i] - Mnew);
      ls += p;
      // adaptive-span soft mask (post-softmax numerator; S stays unmasked)
      const float tpl = (float)(l0 + sj*8 + i) - 1023.0f;
      float mv = (tpl + span * 1024.0f) * 0.03125f + 1.0f;
      mv = fminf(fmaxf(mv, 0.0f), 1.0f);
      pwrow[i] = __float2bfloat16(p * mv);
    }
    ls += __shfl_xor(ls, 1);
    ls += __shfl_xor(ls, 2);
    ls += __shfl_xor(ls, 4);
    Srun = Srun * alpha + ls;
    Mrun = Mnew;
    if (sj == 0) { alpha_lds[srow] = alpha; S_lds[srow] = Srun; }
    __syncthreads();

    // ---- phase 3: rescale O, PV MFMA (k 64..95 of P is zero -> harmless) ----
    float al[4];
#pragma unroll
    for (int r = 0; r < 4; ++r) al[r] = alpha_lds[wr + r];
#pragma unroll
    for (int r = 0; r < 4; ++r) { o0[r] *= al[r]; o1[r] *= al[r]; }
#pragma unroll
    for (int ks = 0; ks < 3; ++ks) {
      const bf16x8 ap = ld8any(&P_lds[col16][ks*32 + kq]);
      const bf16* v0 = vb + (size_t)(dt0 + col16) * SN + nb_ + ks*32 + kq;
      const bf16* v1 = vb + (size_t)(dt1 + col16) * SN + nb_ + ks*32 + kq;
      o0 = mfma16(ap, ld8any(v0), o0);
      o1 = mfma16(ap, ld8any(v1), o1);
    }
    // no barrier: next phase-1 writes cont/pos only; P/alpha rewritten only
    // after the next phase-1 barrier.
  }

  // ---- epilogue: O / S -> ctx[b*512 + m][h*64+d] (bf16) ----
  bf16* cr = ctx + (size_t)(b*SM + m0 + wr) * SH + h*HD + col16;
#pragma unroll
  for (int r = 0; r < 4; ++r) {
    const float inv = 1.0f / S_lds[wr + r];
    cr[(size_t)r * SH + dt0] = __float2bfloat16(o0[r] * inv);
    cr[(size_t)r * SH + dt1] = __float2bfloat16(o1[r] * inv);
  }
}

// ---------------------------------------------------------------------------
extern "C" void kernel_launch(void* const* d_in, const int* in_sizes, int n_in,
                              void* d_out, int out_size, void* d_ws, size_t ws_size,
                              hipStream_t stream) {
  const float* query  = (const float*)d_in[0];   // [8, 512, 512]
  const float* key    = (const float*)d_in[1];   // [8, 1536, 512]
  const float* value  = (const float*)d_in[2];   // [8, 1536, 512]
  const float* key_pe = (const float*)d_in[3];   // [1, 64, 1024]
  const float* Wq     = (const float*)d_in[4];   // [512, 512]
  const float* Wk     = (const float*)d_in[5];
  const float* Wv     = (const float*)d_in[6];
  const float* Wo     = (const float*)d_in[7];
  const float* spanv  = (const float*)d_in[8];   // [8]
  float* out = (float*)d_out;

  bf16* ws = (bf16*)d_ws;
  if (ws_size >= (size_t)33685504) {
    // Path A: precomputed q_proj. 6 dispatches, 33.7 MB ws.
    bf16* k_head = ws;                    // [64*1536, 64]
    bf16* vT     = k_head + 6291456;      // [64*64, 1536]
    bf16* ctx    = vT     + 6291456;      // [8*512, 512]
    bf16* qp     = ctx    + 2097152;      // [8*512, 512]
    bf16* peT    = qp     + 2097152;      // [1024, 64]
    gemm128<1, float, float, bf16><<<384, 256, 0, stream>>>(key,   Wk, k_head);
    gemm128<2, float, float, bf16><<<384, 256, 0, stream>>>(value, Wv, vT);
    gemm128<0, float, float, bf16><<<128, 256, 0, stream>>>(query, Wq, qp);
    transpose_pe<<<256, 256, 0, stream>>>(key_pe, peT);
    attn_kernel<0><<<2048, 128, 0, stream>>>(nullptr, nullptr, qp, k_head, vT,
                                             peT, spanv, ctx);
    gemm128<0, bf16, float, float><<<128, 256, 0, stream>>>(ctx, Wo, out);
  } else {
    // Path B: fused-q attention. 5 dispatches, 29.5 MB ws.
    bf16* k_head = ws;                    // [64*1536, 64]
    bf16* vT     = k_head + 6291456;      // [64*64, 1536]
    bf16* ctx    = vT     + 6291456;      // [8*512, 512]
    bf16* peT    = ctx    + 2097152;      // [1024, 64]
    gemm128<1, float, float, bf16><<<384, 256, 0, stream>>>(key,   Wk, k_head);
    gemm128<2, float, float, bf16><<<384, 256, 0, stream>>>(value, Wv, vT);
    transpose_pe<<<256, 256, 0, stream>>>(key_pe, peT);
    attn_kernel<1><<<2048, 128, 0, stream>>>(query, Wq, nullptr, k_head, vT,
                                             peT, spanv, ctx);
    gemm128<0, bf16, float, float><<<128, 256, 0, stream>>>(ctx, Wo, out);
  }
}